// Round 11
// baseline (122.331 us; speedup 1.0000x reference)
//
#include <hip/hip_runtime.h>
#include <hip/hip_fp16.h>

#define D 128
#define LOG2E 1.4426950408889634f
#define LN2   0.6931471805599453f
#define SLSH   13     // slice = c >> 13 -> 8192 rows = 2MB fp16 (2 fit per XCD L2)
#define NSL    16     // slice slots allocated (13 used at V=100001)
#define SEGCAP 512    // staged candidates per segment; overflow -> tail loop

// K0: fp32->fp16 convert tpl table + segment bounds (fused, streaming).
__global__ __launch_bounds__(256) void prep_kernel(
    const float4* __restrict__ tpl_src,
    uint2* __restrict__ tpl_dst,
    const int* __restrict__ seg_ids,
    int* __restrict__ seg_start,
    int nt4, int T, int B)
{
    const int stride = gridDim.x * blockDim.x;
    const int tid0 = blockIdx.x * blockDim.x + threadIdx.x;

    for (int i = tid0; i < nt4; i += stride) {
        const float4 v = tpl_src[i];
        const __half2 h01 = __float22half2_rn(make_float2(v.x, v.y));
        const __half2 h23 = __float22half2_rn(make_float2(v.z, v.w));
        uint2 o;
        o.x = *reinterpret_cast<const unsigned*>(&h01);
        o.y = *reinterpret_cast<const unsigned*>(&h23);
        tpl_dst[i] = o;
    }
    for (int t = tid0; t < T; t += stride) {
        if (t == 0) seg_start[0] = 0;
        else if (seg_ids[t] != seg_ids[t - 1]) seg_start[seg_ids[t]] = t;
        if (t == T - 1) seg_start[B] = T;
    }
}

// K1 (fused, slice-phased): block = 4 waves = 4 segments. Stage each segment's
// candidate list into LDS counting-sorted by table slice (c>>SLSH). All waves
// then walk slices in the same order -> at any instant the whole GPU gathers
// from one ~2MB tpl window, which is L2-resident in every XCD -> gather
// latency drops from L3 (~600cy) to L2 (~250cy), lifting the MSHR-bound
// gather rate. One wave per segment, 4 quarter-slots = 4 candidates per
// gather instruction (converged), online softmax per slot, merged by shuffle.
__global__ __launch_bounds__(256) void fused_kernel(
    const float* __restrict__ graph_embed,
    const __half* __restrict__ tpl_h,
    const int* __restrict__ cand_idx,
    const int* __restrict__ seg_start,
    const int* __restrict__ target_pos,
    float* __restrict__ out,
    int B, int nsl)
{
    __shared__ int2 ent[4 * SEGCAP];   // 16 KB: staged (cand, t) per segment
    __shared__ int  hist[4][NSL];
    __shared__ int  sbase[4][NSL];
    __shared__ int  scnt[4][NSL];

    const int tid = threadIdx.x;
    const int b0  = blockIdx.x * 4;

    if (tid < 4 * NSL) ((int*)hist)[tid] = 0;
    __syncthreads();

    // count slice histogram per segment
    for (int ls = 0; ls < 4; ++ls) {
        const int b = b0 + ls;
        if (b >= B) continue;
        const int st  = seg_start[b];
        const int len = min(seg_start[b + 1] - st, SEGCAP);
        for (int j = tid; j < len; j += 256)
            atomicAdd(&hist[ls][cand_idx[st + j] >> SLSH], 1);
    }
    __syncthreads();

    // exclusive scan within each segment's 16 slice bins (first wave)
    if (tid < 64) {
        const int ls = tid >> 4, sl = tid & 15;
        const int v = hist[ls][sl];
        int sum = v;
        #pragma unroll
        for (int off = 1; off < 16; off <<= 1) {
            const int up = __shfl_up(sum, off);
            if ((tid & 15) >= off) sum += up;
        }
        sbase[ls][sl] = sum - v;
        scnt[ls][sl]  = v;
        hist[ls][sl]  = 0;   // reuse as scatter cursor
    }
    __syncthreads();

    // scatter (cand, t) into slice-sorted LDS lists
    for (int ls = 0; ls < 4; ++ls) {
        const int b = b0 + ls;
        if (b >= B) continue;
        const int st  = seg_start[b];
        const int len = min(seg_start[b + 1] - st, SEGCAP);
        for (int j = tid; j < len; j += 256) {
            const int c  = cand_idx[st + j];
            const int sl = c >> SLSH;
            const int r  = atomicAdd(&hist[ls][sl], 1);
            ent[ls * SEGCAP + sbase[ls][sl] + r] = make_int2(c, st + j);
        }
    }
    __syncthreads();

    // main: one wave per segment, 4 quarter-slots per wave
    const int wls  = tid >> 6;   // wave index = local segment
    const int lane = tid & 63;
    const int q    = lane >> 4;  // slot 0..3
    const int sl16 = lane & 15;  // lane in quarter (16 x 16B = 256B fp16 row)
    const int b    = b0 + wls;

    float m = -3.0e38f, s = 0.0f, tgt = -3.0e38f;

    if (b < B) {
        const int st  = seg_start[b];
        const int end = seg_start[b + 1];
        const int tp  = target_pos[b];

        // fp32 graph row, loaded once (all 4 slots share it -> L1 broadcast)
        const float4* grow = (const float4*)(graph_embed + (size_t)b * D);
        const float4 ga = grow[sl16 * 2];
        const float4 gb = grow[sl16 * 2 + 1];

        auto dotupd = [&](int c, int t) {
            const uint4 xr = ((const uint4*)(tpl_h + (size_t)c * D))[sl16];
            const __half2* xh = (const __half2*)&xr;
            const float2 f0 = __half22float2(xh[0]);
            const float2 f1 = __half22float2(xh[1]);
            const float2 f2 = __half22float2(xh[2]);
            const float2 f3 = __half22float2(xh[3]);
            float p = ga.x * f0.x;
            p = fmaf(ga.y, f0.y, p);
            p = fmaf(ga.z, f1.x, p);
            p = fmaf(ga.w, f1.y, p);
            p = fmaf(gb.x, f2.x, p);
            p = fmaf(gb.y, f2.y, p);
            p = fmaf(gb.z, f3.x, p);
            p = fmaf(gb.w, f3.y, p);
            #pragma unroll
            for (int off = 8; off >= 1; off >>= 1) p += __shfl_xor(p, off);
            p *= LOG2E;
            if (t == tp) tgt = p;
            const float M = fmaxf(m, p);
            s = fmaf(s, exp2f(m - M), exp2f(p - M));
            m = M;
        };

        #pragma unroll 1
        for (int ps = 0; ps < nsl; ++ps) {
            const int n  = scnt[wls][ps];
            const int bs = wls * SEGCAP + sbase[wls][ps];
            for (int i = q; i < n; i += 4) {
                const int2 e = ent[bs + i];
                dotupd(e.x, e.y);
            }
        }
        // overflow tail (segment longer than SEGCAP; unsliced, converged)
        for (int t0 = st + SEGCAP; t0 < end; t0 += 4) {
            const int t = t0 + q;
            if (t < end) dotupd(cand_idx[t], t);
        }
    }

    // merge the 4 slots within the wave (values uniform within each slot)
    #pragma unroll
    for (int off = 16; off <= 32; off <<= 1) {
        const float m2 = __shfl_xor(m, off);
        const float s2 = __shfl_xor(s, off);
        const float M  = fmaxf(m, m2);
        s = s * exp2f(m - M) + s2 * exp2f(m2 - M);
        m = M;
        tgt = fmaxf(tgt, __shfl_xor(tgt, off));
    }

    if (b < B && lane == 0)
        out[b] = (tgt - m - log2f(s)) * LN2;
}

// ---------- Fallback (fp32, no workspace staging) ----------
__global__ void seg_bounds_kernel(const int* __restrict__ seg_ids,
                                  int* __restrict__ seg_start,
                                  int T, int B) {
    int t = blockIdx.x * blockDim.x + threadIdx.x;
    if (t >= T) return;
    if (t == 0) seg_start[0] = 0;
    else if (seg_ids[t] != seg_ids[t - 1]) seg_start[seg_ids[t]] = t;
    if (t == T - 1) seg_start[B] = T;
}

__global__ __launch_bounds__(256) void logits_kernel(
    const float* __restrict__ graph_embed,
    const float* __restrict__ tpl_embedding,
    const int* __restrict__ cand_idx,
    const int* __restrict__ seg_ids,
    float* __restrict__ logits,
    int T)
{
    const int sl  = threadIdx.x & 31;
    const int hw  = (blockIdx.x * blockDim.x + threadIdx.x) >> 5;
    const int nhw = (gridDim.x * blockDim.x) >> 5;

    for (int t0 = hw; t0 < T; t0 += 2 * nhw) {
        const int t1 = t0 + nhw;
        const bool has1 = (t1 < T);
        const int c0 = cand_idx[t0];
        const int s0 = seg_ids[t0];
        const int c1 = has1 ? cand_idx[t1] : c0;
        const int s1 = has1 ? seg_ids[t1] : s0;

        const float4 x0 = ((const float4*)(tpl_embedding + (size_t)c0 * D))[sl];
        const float4 g0 = ((const float4*)(graph_embed   + (size_t)s0 * D))[sl];
        const float4 x1 = ((const float4*)(tpl_embedding + (size_t)c1 * D))[sl];
        const float4 g1 = ((const float4*)(graph_embed   + (size_t)s1 * D))[sl];

        float p0 = fmaf(g0.x, x0.x, fmaf(g0.y, x0.y, fmaf(g0.z, x0.z, g0.w * x0.w)));
        float p1 = fmaf(g1.x, x1.x, fmaf(g1.y, x1.y, fmaf(g1.z, x1.z, g1.w * x1.w)));

        #pragma unroll
        for (int off = 16; off >= 1; off >>= 1) {
            p0 += __shfl_xor(p0, off);
            p1 += __shfl_xor(p1, off);
        }
        if (sl == 0) {
            logits[t0] = p0;
            if (has1) logits[t1] = p1;
        }
    }
}

__global__ __launch_bounds__(256) void seg_reduce_kernel(
    const float* __restrict__ logits,
    const int* __restrict__ seg_start,
    const int* __restrict__ target_pos,
    float* __restrict__ out,
    int B)
{
    const int wave = threadIdx.x >> 6;
    const int lane = threadIdx.x & 63;
    const int b    = blockIdx.x * 4 + wave;
    if (b >= B) return;

    const int start = seg_start[b];
    const int end   = seg_start[b + 1];

    float m = -3.0e38f;
    float s = 0.0f;

    for (int t = start + lane; t < end; t += 64) {
        const float x = logits[t] * LOG2E;
        if (x <= m) {
            s += exp2f(x - m);
        } else {
            s = fmaf(s, exp2f(m - x), 1.0f);
            m = x;
        }
    }

    #pragma unroll
    for (int off = 32; off >= 1; off >>= 1) {
        const float m2 = __shfl_xor(m, off);
        const float s2 = __shfl_xor(s, off);
        const float M  = fmaxf(m, m2);
        s = s * exp2f(m - M) + s2 * exp2f(m2 - M);
        m = M;
    }

    if (lane == 0) {
        const float tl = logits[target_pos[b]] * LOG2E;
        out[b] = (tl - m - log2f(s)) * LN2;
    }
}

extern "C" void kernel_launch(void* const* d_in, const int* in_sizes, int n_in,
                              void* d_out, int out_size, void* d_ws, size_t ws_size,
                              hipStream_t stream) {
    const float* graph_embed   = (const float*)d_in[0];
    const float* tpl_embedding = (const float*)d_in[1];
    const int*   cand_idx      = (const int*)d_in[2];
    const int*   seg_ids       = (const int*)d_in[3];
    const int*   target_pos    = (const int*)d_in[4];
    float*       out           = (float*)d_out;

    const int BE = in_sizes[0];       // B*D
    const int B  = BE / D;            // 8192
    const int VE = in_sizes[1];       // (V+1)*D
    const int V1 = VE / D;            // 100001
    const int T  = in_sizes[2];       // 524288

    const int nsl = (V1 + (1 << SLSH) - 1) >> SLSH;   // 13

    size_t off = 0;
    auto alloc = [&](size_t bytes) {
        void* p = (char*)d_ws + off;
        off += (bytes + 255) & ~(size_t)255;
        return p;
    };
    int*    seg_start = (int*)   alloc((size_t)(B + 1) * 4);
    __half* tpl_h     = (__half*)alloc((size_t)VE * 2);
    float*  logits    = (float*) alloc((size_t)T * 4);   // fallback only

    if (off <= ws_size && nsl <= NSL) {
        prep_kernel<<<2048, 256, 0, stream>>>((const float4*)tpl_embedding,
                                              (uint2*)tpl_h,
                                              seg_ids, seg_start,
                                              VE / 4, T, B);
        fused_kernel<<<(B + 3) / 4, 256, 0, stream>>>(graph_embed, tpl_h,
                                                      cand_idx, seg_start,
                                                      target_pos, out, B, nsl);
    } else {
        seg_bounds_kernel<<<(T + 255) / 256, 256, 0, stream>>>(seg_ids, seg_start, T, B);
        logits_kernel<<<2048, 256, 0, stream>>>(graph_embed, tpl_embedding,
                                                cand_idx, seg_ids, logits, T);
        seg_reduce_kernel<<<(B + 3) / 4, 256, 0, stream>>>(logits, seg_start,
                                                           target_pos, out, B);
    }
}

// Round 12
// 117.462 us; speedup vs baseline: 1.0415x; 1.0415x over previous
//
#include <hip/hip_runtime.h>
#include <hip/hip_fp16.h>

#define D 128
#define LOG2E 1.4426950408889634f
#define LN2   0.6931471805599453f

// K0: fp32->fp16 convert tpl table + segment bounds (fused, streaming).
// 79MB of traffic at ~6.3TB/s -> at HBM roofline.
__global__ __launch_bounds__(256) void prep_kernel(
    const float4* __restrict__ tpl_src,
    uint2* __restrict__ tpl_dst,
    const int* __restrict__ seg_ids,
    int* __restrict__ seg_start,
    int nt4, int T, int B)
{
    const int stride = gridDim.x * blockDim.x;
    const int tid0 = blockIdx.x * blockDim.x + threadIdx.x;

    for (int i = tid0; i < nt4; i += stride) {
        const float4 v = tpl_src[i];
        const __half2 h01 = __float22half2_rn(make_float2(v.x, v.y));
        const __half2 h23 = __float22half2_rn(make_float2(v.z, v.w));
        uint2 o;
        o.x = *reinterpret_cast<const unsigned*>(&h01);
        o.y = *reinterpret_cast<const unsigned*>(&h23);
        tpl_dst[i] = o;
    }
    for (int t = tid0; t < T; t += stride) {
        if (t == 0) seg_start[0] = 0;
        else if (seg_ids[t] != seg_ids[t - 1]) seg_start[seg_ids[t]] = t;
        if (t == T - 1) seg_start[B] = T;
    }
}

// K1 (fused gather + online softmax + output):
// Each segment is split across 4 quarter-waves (part 0..3, stride-4 over its
// candidates). A quarter-wave (16 lanes x 16B) holds the segment's fp32 graph
// row in registers and issues EXACTLY ONE gather (256B fp16 tpl row) per
// candidate. Two independent branchless online-softmax chains per
// quarter-wave for load pipelining. 4 partials per segment merged via LDS;
// out[b] written directly. No logits buffer.
// Gather throughput sits at the MSHR x L3-latency cap (~5.4 TB/s effective);
// reordering schemes to make gathers L2-hit were tried 4x and all regressed.
__global__ __launch_bounds__(256) void fused_kernel(
    const float* __restrict__ graph_embed,
    const __half* __restrict__ tpl_h,
    const int* __restrict__ cand_idx,
    const int* __restrict__ seg_start,
    const int* __restrict__ target_pos,
    float* __restrict__ out,
    int B)
{
    const int sl   = threadIdx.x & 15;   // lane in quarter-wave
    const int q    = threadIdx.x >> 4;   // quarter id in block: 0..15
    const int lseg = q >> 2;             // local segment 0..3
    const int part = q & 3;              // which quarter of the segment
    const int b    = blockIdx.x * 4 + lseg;
    if (b >= B) return;

    const int start = seg_start[b];
    const int end   = seg_start[b + 1];
    const int tp    = target_pos[b];

    // fp32 graph row: 2 x float4 per lane, loaded once per segment.
    const float4* grow = (const float4*)(graph_embed + (size_t)b * D);
    const float4 ga = grow[sl * 2];
    const float4 gb = grow[sl * 2 + 1];

    float mA = -3.0e38f, sA = 0.0f;
    float mB = -3.0e38f, sB = 0.0f;
    float tgt = -3.0e38f;

    auto body = [&](int t, float& m, float& s) {
        const int c = cand_idx[t];
        const uint4 xr = ((const uint4*)(tpl_h + (size_t)c * D))[sl];
        const __half2* xh = (const __half2*)&xr;
        const float2 f0 = __half22float2(xh[0]);
        const float2 f1 = __half22float2(xh[1]);
        const float2 f2 = __half22float2(xh[2]);
        const float2 f3 = __half22float2(xh[3]);
        float p = ga.x * f0.x;
        p = fmaf(ga.y, f0.y, p);
        p = fmaf(ga.z, f1.x, p);
        p = fmaf(ga.w, f1.y, p);
        p = fmaf(gb.x, f2.x, p);
        p = fmaf(gb.y, f2.y, p);
        p = fmaf(gb.z, f3.x, p);
        p = fmaf(gb.w, f3.y, p);
        #pragma unroll
        for (int off = 8; off >= 1; off >>= 1) p += __shfl_xor(p, off);
        p *= LOG2E;
        if (t == tp) tgt = p;
        const float M = fmaxf(m, p);
        s = fmaf(s, exp2f(m - M), exp2f(p - M));
        m = M;
    };

    int t = start + part;
    for (; t + 4 < end; t += 8) {
        body(t, mA, sA);
        body(t + 4, mB, sB);
    }
    if (t < end) body(t, mA, sA);

    // merge chains A,B
    const float Mq = fmaxf(mA, mB);
    const float Sq = sA * exp2f(mA - Mq) + sB * exp2f(mB - Mq);

    // merge the 4 parts of each segment via LDS
    __shared__ float sm[16], ss[16], st[16];
    if (sl == 0) { sm[q] = Mq; ss[q] = Sq; st[q] = tgt; }
    __syncthreads();

    if (threadIdx.x < 4) {
        const int bo = blockIdx.x * 4 + threadIdx.x;
        if (bo < B) {
            const int base = threadIdx.x * 4;
            float M = -3.0e38f;
            #pragma unroll
            for (int j = 0; j < 4; ++j) M = fmaxf(M, sm[base + j]);
            float S = 0.0f, Tg = -3.0e38f;
            #pragma unroll
            for (int j = 0; j < 4; ++j) {
                S += ss[base + j] * exp2f(sm[base + j] - M);
                Tg = fmaxf(Tg, st[base + j]);
            }
            out[bo] = (Tg - M - log2f(S)) * LN2;
        }
    }
}

// ---------- Fallback (fp32, no workspace staging) ----------
__global__ void seg_bounds_kernel(const int* __restrict__ seg_ids,
                                  int* __restrict__ seg_start,
                                  int T, int B) {
    int t = blockIdx.x * blockDim.x + threadIdx.x;
    if (t >= T) return;
    if (t == 0) seg_start[0] = 0;
    else if (seg_ids[t] != seg_ids[t - 1]) seg_start[seg_ids[t]] = t;
    if (t == T - 1) seg_start[B] = T;
}

__global__ __launch_bounds__(256) void logits_kernel(
    const float* __restrict__ graph_embed,
    const float* __restrict__ tpl_embedding,
    const int* __restrict__ cand_idx,
    const int* __restrict__ seg_ids,
    float* __restrict__ logits,
    int T)
{
    const int sl  = threadIdx.x & 31;
    const int hw  = (blockIdx.x * blockDim.x + threadIdx.x) >> 5;
    const int nhw = (gridDim.x * blockDim.x) >> 5;

    for (int t0 = hw; t0 < T; t0 += 2 * nhw) {
        const int t1 = t0 + nhw;
        const bool has1 = (t1 < T);
        const int c0 = cand_idx[t0];
        const int s0 = seg_ids[t0];
        const int c1 = has1 ? cand_idx[t1] : c0;
        const int s1 = has1 ? seg_ids[t1] : s0;

        const float4 x0 = ((const float4*)(tpl_embedding + (size_t)c0 * D))[sl];
        const float4 g0 = ((const float4*)(graph_embed   + (size_t)s0 * D))[sl];
        const float4 x1 = ((const float4*)(tpl_embedding + (size_t)c1 * D))[sl];
        const float4 g1 = ((const float4*)(graph_embed   + (size_t)s1 * D))[sl];

        float p0 = fmaf(g0.x, x0.x, fmaf(g0.y, x0.y, fmaf(g0.z, x0.z, g0.w * x0.w)));
        float p1 = fmaf(g1.x, x1.x, fmaf(g1.y, x1.y, fmaf(g1.z, x1.z, g1.w * x1.w)));

        #pragma unroll
        for (int off = 16; off >= 1; off >>= 1) {
            p0 += __shfl_xor(p0, off);
            p1 += __shfl_xor(p1, off);
        }
        if (sl == 0) {
            logits[t0] = p0;
            if (has1) logits[t1] = p1;
        }
    }
}

__global__ __launch_bounds__(256) void seg_reduce_kernel(
    const float* __restrict__ logits,
    const int* __restrict__ seg_start,
    const int* __restrict__ target_pos,
    float* __restrict__ out,
    int B)
{
    const int wave = threadIdx.x >> 6;
    const int lane = threadIdx.x & 63;
    const int b    = blockIdx.x * 4 + wave;
    if (b >= B) return;

    const int start = seg_start[b];
    const int end   = seg_start[b + 1];

    float m = -3.0e38f;
    float s = 0.0f;

    for (int t = start + lane; t < end; t += 64) {
        const float x = logits[t] * LOG2E;
        if (x <= m) {
            s += exp2f(x - m);
        } else {
            s = fmaf(s, exp2f(m - x), 1.0f);
            m = x;
        }
    }

    #pragma unroll
    for (int off = 32; off >= 1; off >>= 1) {
        const float m2 = __shfl_xor(m, off);
        const float s2 = __shfl_xor(s, off);
        const float M  = fmaxf(m, m2);
        s = s * exp2f(m - M) + s2 * exp2f(m2 - M);
        m = M;
    }

    if (lane == 0) {
        const float tl = logits[target_pos[b]] * LOG2E;
        out[b] = (tl - m - log2f(s)) * LN2;
    }
}

extern "C" void kernel_launch(void* const* d_in, const int* in_sizes, int n_in,
                              void* d_out, int out_size, void* d_ws, size_t ws_size,
                              hipStream_t stream) {
    const float* graph_embed   = (const float*)d_in[0];
    const float* tpl_embedding = (const float*)d_in[1];
    const int*   cand_idx      = (const int*)d_in[2];
    const int*   seg_ids       = (const int*)d_in[3];
    const int*   target_pos    = (const int*)d_in[4];
    float*       out           = (float*)d_out;

    const int BE = in_sizes[0];       // B*D
    const int B  = BE / D;            // 8192
    const int VE = in_sizes[1];       // (V+1)*D
    const int T  = in_sizes[2];       // 524288

    size_t off = 0;
    auto alloc = [&](size_t bytes) {
        void* p = (char*)d_ws + off;
        off += (bytes + 255) & ~(size_t)255;
        return p;
    };
    int*    seg_start = (int*)   alloc((size_t)(B + 1) * 4);
    __half* tpl_h     = (__half*)alloc((size_t)VE * 2);
    float*  logits    = (float*) alloc((size_t)T * 4);   // fallback only

    if (off <= ws_size) {
        prep_kernel<<<2048, 256, 0, stream>>>((const float4*)tpl_embedding,
                                              (uint2*)tpl_h,
                                              seg_ids, seg_start,
                                              VE / 4, T, B);
        fused_kernel<<<(B + 3) / 4, 256, 0, stream>>>(graph_embed, tpl_h,
                                                      cand_idx, seg_start,
                                                      target_pos, out, B);
    } else {
        seg_bounds_kernel<<<(T + 255) / 256, 256, 0, stream>>>(seg_ids, seg_start, T, B);
        logits_kernel<<<2048, 256, 0, stream>>>(graph_embed, tpl_embedding,
                                                cand_idx, seg_ids, logits, T);
        seg_reduce_kernel<<<(B + 3) / 4, 256, 0, stream>>>(logits, seg_start,
                                                           target_pos, out, B);
    }
}